// Round 16
// baseline (249.860 us; speedup 1.0000x reference)
//
#include <hip/hip_runtime.h>
#include <hip/hip_bf16.h>

typedef short bf16x8 __attribute__((ext_vector_type(8)));
typedef float f32x4  __attribute__((ext_vector_type(4)));
typedef unsigned int u32;

#define LSEQ 2048
#define DDIM 512
#define NBAT 8

__device__ __forceinline__ void gld_lds16(const void* g, void* l) {
    __builtin_amdgcn_global_load_lds(
        (const __attribute__((address_space(1))) u32*)g,
        (__attribute__((address_space(3))) u32*)l, 16, 0, 0);
}
__device__ __forceinline__ float bf2f(short s) {
    u32 u = ((u32)(unsigned short)s) << 16;
    union { u32 u; float f; } c; c.u = u; return c.f;
}
__device__ __forceinline__ short f2bf(float f) {
    __hip_bfloat16 h = __float2bfloat16(f);
    return *(short*)&h;
}

// ---------------- merged conversions: blocks [0,1024) transpose W, rest convert x ----------------
__global__ void k_cvt(const float* __restrict__ x, const float* __restrict__ Wq,
                      const float* __restrict__ Wk, const float* __restrict__ Wv,
                      const float* __restrict__ Wo, __hip_bfloat16* __restrict__ xb,
                      __hip_bfloat16* __restrict__ Wtqkv, __hip_bfloat16* __restrict__ Wto) {
    __shared__ float t[32][33];
    if (blockIdx.x < 1024) {
        int mat = blockIdx.x >> 8;
        int tb  = blockIdx.x & 255;
        int tk  = tb >> 4, tn = tb & 15;
        const float* W = (mat == 0) ? Wq : (mat == 1) ? Wk : (mat == 2) ? Wv : Wo;
        int c  = threadIdx.x & 31;
        int r0 = threadIdx.x >> 5;
#pragma unroll
        for (int i = 0; i < 4; ++i) {
            int r = r0 + i * 8;
            t[r][c] = W[(size_t)(tk * 32 + r) * 512 + tn * 32 + c];
        }
        __syncthreads();
        __hip_bfloat16* dst = (mat < 3) ? (Wtqkv + (size_t)mat * 512 * 512) : Wto;
#pragma unroll
        for (int i = 0; i < 4; ++i) {
            int n = r0 + i * 8;
            dst[(size_t)(tn * 32 + n) * 512 + tk * 32 + c] = __float2bfloat16(t[c][n]);
        }
    } else {
        size_t i = ((size_t)(blockIdx.x - 1024) * 256 + threadIdx.x) * 4;
        float4 v = *(const float4*)(x + i);
        __hip_bfloat16 h[4] = { __float2bfloat16(v.x), __float2bfloat16(v.y),
                                __float2bfloat16(v.z), __float2bfloat16(v.w) };
        *(short4*)(xb + i) = *(short4*)h;
    }
}

// ---------------- fused QKV GEMM: dbuf gld_lds staging, nt-fastest dispatch (A-tile L2 reuse) ----------------
__global__ __launch_bounds__(256, 2)
void k_gemm_qkv(const __hip_bfloat16* __restrict__ A, const __hip_bfloat16* __restrict__ Bt,
                __hip_bfloat16* __restrict__ Q, __hip_bfloat16* __restrict__ Kb,
                __hip_bfloat16* __restrict__ Vt) {
    __shared__ __hip_bfloat16 As[2][128][32], Bs[2][128][32];   // 32 KB
    const int tid = threadIdx.x, lane = tid & 63, w = tid >> 6;
    const int l15 = lane & 15, l4 = lane >> 4;
    const int mt = blockIdx.y, nt = blockIdx.x;   // nt fastest: 12 consecutive blocks share A-tile
    const int wr = (w >> 1) * 64, wc = (w & 1) * 64;
    const int sr = lane >> 2, so = (lane & 3) * 8;
    f32x4 acc[4][4] = {};

    // prologue: stage kt=0 into buf 0
#pragma unroll
    for (int i = 0; i < 2; ++i) {
        int r0 = w * 32 + i * 16;
        gld_lds16(A  + (size_t)(mt * 128 + r0 + sr) * 512 + so, &As[0][r0][0]);
        gld_lds16(Bt + (size_t)(nt * 128 + r0 + sr) * 512 + so, &Bs[0][r0][0]);
    }
    __syncthreads();

#pragma unroll 1
    for (int kt = 0; kt < 16; ++kt) {
        const int cur = kt & 1, nxt = cur ^ 1;
        // issue staging for kt+1 (DMA overlaps MFMA below)
        if (kt < 15) {
#pragma unroll
            for (int i = 0; i < 2; ++i) {
                int r0 = w * 32 + i * 16;
                gld_lds16(A  + (size_t)(mt * 128 + r0 + sr) * 512 + (kt + 1) * 32 + so, &As[nxt][r0][0]);
                gld_lds16(Bt + (size_t)(nt * 128 + r0 + sr) * 512 + (kt + 1) * 32 + so, &Bs[nxt][r0][0]);
            }
        }
        bf16x8 af[4], bfr[4];
#pragma unroll
        for (int i = 0; i < 4; ++i)
            af[i] = *(const bf16x8*)(&As[cur][wr + 16 * i + l15][l4 * 8]);
#pragma unroll
        for (int j = 0; j < 4; ++j)
            bfr[j] = *(const bf16x8*)(&Bs[cur][wc + 16 * j + l15][l4 * 8]);
        __builtin_amdgcn_s_setprio(1);
#pragma unroll
        for (int i = 0; i < 4; ++i)
#pragma unroll
            for (int j = 0; j < 4; ++j)
                acc[i][j] = __builtin_amdgcn_mfma_f32_16x16x32_bf16(af[i], bfr[j], acc[i][j], 0, 0, 0);
        __builtin_amdgcn_s_setprio(0);
        __syncthreads();   // drains DMA (buf nxt ready) + protects buf cur from next stage
    }
    const int which = (nt * 128) >> 9;  // 0=q,1=k,2=v (uniform per block)
#pragma unroll
    for (int i = 0; i < 4; ++i) {
#pragma unroll
        for (int r = 0; r < 4; ++r) {
            int grow = mt * 128 + wr + 16 * i + (l4 << 2) + r;
#pragma unroll
            for (int j = 0; j < 4; ++j) {
                int gcol = nt * 128 + wc + 16 * j + l15;
                int cc = gcol & 511;
                __hip_bfloat16 h = __float2bfloat16(acc[i][j][r]);
                if (which == 0)      Q [(size_t)grow * 512 + cc] = h;
                else if (which == 1) Kb[(size_t)grow * 512 + cc] = h;
                else {
                    int b = grow >> 11, m = grow & 2047;
                    Vt[((size_t)b * 512 + cc) * 2048 + m] = h;
                }
            }
        }
    }
}

// ---------------- flash attention: 8 waves, dbuf KVB=32, all-async staging (R8-proven, FROZEN) ----------------
__global__ __launch_bounds__(512, 2)
void k_attn(const __hip_bfloat16* __restrict__ Q, const __hip_bfloat16* __restrict__ Kg,
            const __hip_bfloat16* __restrict__ Vt, const int* __restrict__ adj,
            __hip_bfloat16* __restrict__ P0, __hip_bfloat16* __restrict__ P1,
            float* __restrict__ mlb) {
    __shared__ __hip_bfloat16 Kl[2][32][520];   // 66,560 B
    __shared__ __hip_bfloat16 Vl[2][512][32];   // 65,536 B (linear 64B rows, swizzled 16B cols)
    __shared__ __hip_bfloat16 Pl[8][16][40];    // 10,240 B => 142,336 B total
    const int tid = threadIdx.x, lane = tid & 63, w = tid >> 6;
    const int l15 = lane & 15, l4 = lane >> 4;
    const int b = blockIdx.x & 7, qt = (blockIdx.x >> 3) & 15, s = blockIdx.x >> 7;
    const float scale = 0.04419417382415922f;  // 1/sqrt(512)
    __hip_bfloat16* __restrict__ Op = s ? P1 : P0;

    const __hip_bfloat16* kbase = Kg + ((size_t)b * LSEQ + s * 1024) * 512;
    const __hip_bfloat16* vbase = Vt + (size_t)b * 512 * 2048 + s * 1024;
    const int* abase = adj + ((size_t)b * LSEQ + qt * 128 + w * 16 + l4 * 4) * LSEQ + s * 1024 + l15;
    const int vsr = lane >> 2;                       // V staging row within 16-row chunk
    const int vswz = (l4 ^ ((l15 >> 1) & 3)) * 8;    // PV read swizzle (element offset)

    // Q fragments in registers: wave's 16 rows x 512 k
    bf16x8 qf[16];
    {
        const __hip_bfloat16* qp = Q + ((size_t)b * LSEQ + qt * 128 + w * 16 + l15) * 512;
#pragma unroll
        for (int ks = 0; ks < 16; ++ks)
            qf[ks] = *(const bf16x8*)(qp + ks * 32 + l4 * 8);
    }
    f32x4 acc[32];
#pragma unroll
    for (int n = 0; n < 32; ++n) acc[n] = (f32x4){0.f, 0.f, 0.f, 0.f};
    float m_[4] = {-1e30f, -1e30f, -1e30f, -1e30f};
    float l_[4] = {0.f, 0.f, 0.f, 0.f};

    int adjv[8];
    // ---- prologue: stage tile 0 into buf 0 ----
    {
#pragma unroll
        for (int i = 0; i < 4; ++i) {
            int r = w + i * 8;
            gld_lds16(kbase + (size_t)r * 512 + lane * 8, &Kl[0][r][0]);
        }
#pragma unroll
        for (int i = 0; i < 4; ++i) {
            int r0 = (w * 4 + i) * 16;
            int d  = r0 + vsr;
            gld_lds16(vbase + (size_t)d * 2048 + (((lane & 3) ^ ((d >> 1) & 3)) << 3), &Vl[0][r0][0]);
        }
#pragma unroll
        for (int r = 0; r < 4; ++r)
#pragma unroll
            for (int n = 0; n < 2; ++n)
                adjv[r * 2 + n] = abase[(size_t)r * LSEQ + n * 16];
    }
    __syncthreads();   // drains all global_load_lds

#pragma unroll 1
    for (int t = 0; t < 32; ++t) {
        const int cur = t & 1, nxt = cur ^ 1;
        unsigned amask = 0;
#pragma unroll
        for (int r = 0; r < 4; ++r)
#pragma unroll
            for (int n = 0; n < 2; ++n)
                amask |= (adjv[r * 2 + n] != 0 ? 1u : 0u) << (n * 4 + r);
        // ---- issue staging for t+1 (overlaps with compute below) ----
        if (t < 31) {
            const __hip_bfloat16* kp = kbase + (size_t)(t + 1) * 32 * 512;
#pragma unroll
            for (int i = 0; i < 4; ++i) {
                int r = w + i * 8;
                gld_lds16(kp + (size_t)r * 512 + lane * 8, &Kl[nxt][r][0]);
            }
            const __hip_bfloat16* vp = vbase + (t + 1) * 32;
#pragma unroll
            for (int i = 0; i < 4; ++i) {
                int r0 = (w * 4 + i) * 16;
                int d  = r0 + vsr;
                gld_lds16(vp + (size_t)d * 2048 + (((lane & 3) ^ ((d >> 1) & 3)) << 3), &Vl[nxt][r0][0]);
            }
            const int* ap = abase + (t + 1) * 32;
#pragma unroll
            for (int r = 0; r < 4; ++r)
#pragma unroll
                for (int n = 0; n < 2; ++n)
                    adjv[r * 2 + n] = ap[(size_t)r * LSEQ + n * 16];
        }
        // ---- QK^T on buf cur: wave's 16 rows x 32 keys ----
        f32x4 sa[2];
#pragma unroll
        for (int n = 0; n < 2; ++n) sa[n] = (f32x4){0.f, 0.f, 0.f, 0.f};
        __builtin_amdgcn_s_setprio(1);
#pragma unroll
        for (int ks = 0; ks < 16; ++ks) {
#pragma unroll
            for (int n = 0; n < 2; ++n) {
                bf16x8 bk = *(const bf16x8*)(&Kl[cur][n * 16 + l15][ks * 32 + l4 * 8]);
                sa[n] = __builtin_amdgcn_mfma_f32_16x16x32_bf16(qf[ks], bk, sa[n], 0, 0, 0);
            }
        }
        __builtin_amdgcn_s_setprio(0);
        // masked row max
        float mx[4];
#pragma unroll
        for (int r = 0; r < 4; ++r) {
            float v = -1e30f;
#pragma unroll
            for (int n = 0; n < 2; ++n)
                if ((amask >> (n * 4 + r)) & 1) v = fmaxf(v, sa[n][r] * scale);
            v = fmaxf(v, __shfl_xor(v, 1));
            v = fmaxf(v, __shfl_xor(v, 2));
            v = fmaxf(v, __shfl_xor(v, 4));
            v = fmaxf(v, __shfl_xor(v, 8));
            mx[r] = v;
        }
        // deferred-max online softmax (THR=8)
        float rs[4];
        bool need = false;
#pragma unroll
        for (int r = 0; r < 4; ++r) {
            rs[r] = 1.f;
            if (mx[r] > m_[r] + 8.f) { rs[r] = __expf(m_[r] - mx[r]); m_[r] = mx[r]; }
            l_[r] *= rs[r];
            need |= (rs[r] != 1.f);
        }
        if (need) {
#pragma unroll
            for (int n = 0; n < 32; ++n) {
                acc[n][0] *= rs[0]; acc[n][1] *= rs[1];
                acc[n][2] *= rs[2]; acc[n][3] *= rs[3];
            }
        }
        // p = exp(s - m) (masked -> 0); row sums
#pragma unroll
        for (int n = 0; n < 2; ++n)
#pragma unroll
            for (int r = 0; r < 4; ++r) {
                float p = ((amask >> (n * 4 + r)) & 1) ? __expf(sa[n][r] * scale - m_[r]) : 0.f;
                sa[n][r] = p;
            }
#pragma unroll
        for (int r = 0; r < 4; ++r) {
            float sm = sa[0][r] + sa[1][r];
            sm += __shfl_xor(sm, 1);
            sm += __shfl_xor(sm, 2);
            sm += __shfl_xor(sm, 4);
            sm += __shfl_xor(sm, 8);
            l_[r] += sm;
        }
        // relayout P via per-wave LDS
#pragma unroll
        for (int n = 0; n < 2; ++n)
#pragma unroll
            for (int r = 0; r < 4; ++r)
                Pl[w][l4 * 4 + r][n * 16 + l15] = __float2bfloat16(sa[n][r]);
        // PV accumulate on buf cur (swizzled V read)
        {
            bf16x8 pf = *(const bf16x8*)(&Pl[w][l15][l4 * 8]);
            __builtin_amdgcn_s_setprio(1);
#pragma unroll
            for (int n = 0; n < 32; ++n) {
                bf16x8 bv = *(const bf16x8*)(&Vl[cur][n * 16 + l15][vswz]);
                acc[n] = __builtin_amdgcn_mfma_f32_16x16x32_bf16(pf, bv, acc[n], 0, 0, 0);
            }
            __builtin_amdgcn_s_setprio(0);
        }
        __syncthreads();   // publishes buf nxt
    }
    // epilogue: unnormalized partials + (m,l)
#pragma unroll
    for (int r = 0; r < 4; ++r) {
        size_t row = (size_t)b * LSEQ + qt * 128 + w * 16 + l4 * 4 + r;
#pragma unroll
        for (int n = 0; n < 32; ++n)
            Op[row * 512 + n * 16 + l15] = __float2bfloat16(acc[n][r]);
        if (l15 == 0) {
            mlb[((size_t)s * 16384 + row) * 2 + 0] = m_[r];
            mlb[((size_t)s * 16384 + row) * 2 + 1] = l_[r];
        }
    }
}

// ---------------- fused: combine(LSE) + out-proj + residual + bias + LayerNorm ----------------
// grid 256: block = 64 rows x 512 cols. Double-buffered; A-combine uses T14 load-early/write-late.
__global__ __launch_bounds__(512, 2)
void k_out_ln(const __hip_bfloat16* __restrict__ p0, const __hip_bfloat16* __restrict__ p1,
              const float* __restrict__ mlb, const __hip_bfloat16* __restrict__ Bt,
              const float* __restrict__ x, const float* __restrict__ bo,
              const float* __restrict__ gamma, const float* __restrict__ beta,
              float* __restrict__ out) {
    __shared__ __hip_bfloat16 As[2][64][32];   //  8 KB
    __shared__ __hip_bfloat16 Bs[2][512][32];  // 64 KB
    __shared__ float part[64][4][2];           //  2 KB
    __shared__ float lnmv[64][2];              //  0.5 KB => 74.5 KB
    const int tid = threadIdx.x, lane = tid & 63, w = tid >> 6;
    const int l15 = lane & 15, l4 = lane >> 4;
    const int mt = blockIdx.x;
    const int rs = (w >> 2) * 32, cbs = (w & 3) * 128;
    f32x4 acc[2][8] = {};

    // per-row combine factors (A-staging threads: tid<256, row = tid>>2)
    float c0 = 0.f, c1 = 0.f;
    size_t grow_s = 0;
    int ko = (tid & 3) * 8;
    if (tid < 256) {
        int arow = tid >> 2;
        grow_s = (size_t)mt * 64 + arow;
        float m0 = mlb[grow_s * 2], l0 = mlb[grow_s * 2 + 1];
        float m1 = mlb[(16384 + grow_s) * 2], l1 = mlb[(16384 + grow_s) * 2 + 1];
        float M  = fmaxf(m0, m1);
        float e0 = __expf(m0 - M), e1 = __expf(m1 - M);
        float den = l0 * e0 + l1 * e1;
        float inv = (den > 0.f) ? 1.f / den : 0.f;
        c0 = e0 * inv; c1 = e1 * inv;
    }

    // prologue: stage kt=0 into buf 0
#pragma unroll
    for (int i = 0; i < 4; ++i) {
        int br = w * 64 + i * 16;
        gld_lds16(Bt + (size_t)(br + (lane >> 2)) * 512 + (lane & 3) * 8, &Bs[0][br][0]);
    }
    if (tid < 256) {
        bf16x8 a0 = *(const bf16x8*)(p0 + grow_s * 512 + ko);
        bf16x8 a1 = *(const bf16x8*)(p1 + grow_s * 512 + ko);
        short h[8];
#pragma unroll
        for (int k = 0; k < 8; ++k)
            h[k] = f2bf(c0 * bf2f(((short*)&a0)[k]) + c1 * bf2f(((short*)&a1)[k]));
        *(bf16x8*)(&As[0][tid >> 2][ko]) = *(bf16x8*)h;
    }
    __syncthreads();

#pragma unroll 1
    for (int kt = 0; kt < 16; ++kt) {
        const int cur = kt & 1, nxt = cur ^ 1;
        bf16x8 a0, a1;
        // issue staging for kt+1: B via DMA, A partials into regs (write-late)
        if (kt < 15) {
#pragma unroll
            for (int i = 0; i < 4; ++i) {
                int br = w * 64 + i * 16;
                gld_lds16(Bt + (size_t)(br + (lane >> 2)) * 512 + (kt + 1) * 32 + (lane & 3) * 8,
                          &Bs[nxt][br][0]);
            }
            if (tid < 256) {
                a0 = *(const bf16x8*)(p0 + grow_s * 512 + (kt + 1) * 32 + ko);
                a1 = *(const bf16x8*)(p1 + grow_s * 512 + (kt + 1) * 32 + ko);
            }
        }
        bf16x8 af[2], bfr[8];
#pragma unroll
        for (int i = 0; i < 2; ++i)
            af[i] = *(const bf16x8*)(&As[cur][rs + 16 * i + l15][l4 * 8]);
#pragma unroll
        for (int j = 0; j < 8; ++j)
            bfr[j] = *(const bf16x8*)(&Bs[cur][cbs + 16 * j + l15][l4 * 8]);
        __builtin_amdgcn_s_setprio(1);
#pragma unroll
        for (int i = 0; i < 2; ++i)
#pragma unroll
            for (int j = 0; j < 8; ++j)
                acc[i][j] = __builtin_amdgcn_mfma_f32_16x16x32_bf16(af[i], bfr[j], acc[i][j], 0, 0, 0);
        __builtin_amdgcn_s_setprio(0);
        // A-combine write-late (loads landed under the MFMA block)
        if (kt < 15 && tid < 256) {
            short h[8];
#pragma unroll
            for (int k = 0; k < 8; ++k)
                h[k] = f2bf(c0 * bf2f(((short*)&a0)[k]) + c1 * bf2f(((short*)&a1)[k]));
            *(bf16x8*)(&As[nxt][tid >> 2][ko]) = *(bf16x8*)h;
        }
        __syncthreads();   // drains B-DMA + A ds_writes; protects buf cur
    }
    // pass 1: y = x + acc + bo (into acc), LN partials
#pragma unroll
    for (int i = 0; i < 2; ++i) {
#pragma unroll
        for (int r = 0; r < 4; ++r) {
            int rl = rs + 16 * i + 4 * l4 + r;
            size_t grow = (size_t)mt * 64 + rl;
            float s = 0.f, q = 0.f;
#pragma unroll
            for (int j = 0; j < 8; ++j) {
                int col = cbs + 16 * j + l15;
                float y = x[grow * 512 + col] + acc[i][j][r] + bo[col];
                acc[i][j][r] = y;
                s += y; q += y * y;
            }
            s += __shfl_xor(s, 1); q += __shfl_xor(q, 1);
            s += __shfl_xor(s, 2); q += __shfl_xor(q, 2);
            s += __shfl_xor(s, 4); q += __shfl_xor(q, 4);
            s += __shfl_xor(s, 8); q += __shfl_xor(q, 8);
            if (l15 == 0) { part[rl][w & 3][0] = s; part[rl][w & 3][1] = q; }
        }
    }
    __syncthreads();
    if (tid < 64) {
        float S  = part[tid][0][0] + part[tid][1][0] + part[tid][2][0] + part[tid][3][0];
        float Q2 = part[tid][0][1] + part[tid][1][1] + part[tid][2][1] + part[tid][3][1];
        float mu = S * (1.f / 512.f);
        float var = Q2 * (1.f / 512.f) - mu * mu;
        lnmv[tid][0] = mu;
        lnmv[tid][1] = rsqrtf(var + 1e-5f);
    }
    __syncthreads();
    // pass 2: normalize + store
    float gm[8], bt2[8];
#pragma unroll
    for (int j = 0; j < 8; ++j) {
        int col = cbs + 16 * j + l15;
        gm[j] = gamma[col]; bt2[j] = beta[col];
    }
#pragma unroll
    for (int i = 0; i < 2; ++i) {
#pragma unroll
        for (int r = 0; r < 4; ++r) {
            int rl = rs + 16 * i + 4 * l4 + r;
            size_t grow = (size_t)mt * 64 + rl;
            float mu = lnmv[rl][0], rsd = lnmv[rl][1];
#pragma unroll
            for (int j = 0; j < 8; ++j) {
                int col = cbs + 16 * j + l15;
                out[grow * 512 + col] = (acc[i][j][r] - mu) * rsd * gm[j] + bt2[j];
            }
        }
    }
}

extern "C" void kernel_launch(void* const* d_in, const int* in_sizes, int n_in,
                              void* d_out, int out_size, void* d_ws, size_t ws_size,
                              hipStream_t stream) {
    const float* x     = (const float*)d_in[0];
    const int*   adj   = (const int*)d_in[1];
    const float* Wq    = (const float*)d_in[2];
    const float* Wk    = (const float*)d_in[3];
    const float* Wv    = (const float*)d_in[4];
    const float* Wo    = (const float*)d_in[5];
    const float* bo    = (const float*)d_in[6];
    const float* gamma = (const float*)d_in[7];
    const float* beta  = (const float*)d_in[8];
    float* out = (float*)d_out;

    char* ws = (char*)d_ws;
    const size_t SZ_ROWS = (size_t)NBAT * LSEQ;  // 16384
    __hip_bfloat16* xb    = (__hip_bfloat16*)(ws);              // 16.78 MB; later = partial0
    __hip_bfloat16* Wtqkv = (__hip_bfloat16*)(ws + 16777216);   // 1.57 MB
    __hip_bfloat16* Wto   = (__hip_bfloat16*)(ws + 18350080);   // 0.52 MB
    __hip_bfloat16* Qb    = (__hip_bfloat16*)(ws + 18874368);   // 16.78 MB
    __hip_bfloat16* Kb    = (__hip_bfloat16*)(ws + 35651584);   // 16.78 MB
    __hip_bfloat16* Vtb   = (__hip_bfloat16*)(ws + 52428800);   // 16.78 MB
    __hip_bfloat16* P1    = (__hip_bfloat16*)(ws + 69206016);   // 16.78 MB (partial1)
    float*          mlb   = (float*)         (ws + 85983232);   // 0.26 MB
    __hip_bfloat16* P0    = xb;   // partial0 alias (xb dead after gemm_qkv)
    (void)in_sizes; (void)n_in; (void)out_size; (void)ws_size;

    k_cvt<<<1024 + (unsigned)((SZ_ROWS * DDIM) / (256 * 4)), 256, 0, stream>>>(
        x, Wq, Wk, Wv, Wo, xb, Wtqkv, Wto);
    k_gemm_qkv<<<dim3(12, 128), 256, 0, stream>>>(xb, Wtqkv, Qb, Kb, Vtb);
    k_attn<<<256, 512, 0, stream>>>(Qb, Kb, Vtb, adj, P0, P1, mlb);
    k_out_ln<<<256, 512, 0, stream>>>(P0, P1, mlb, Wto, x, bo, gamma, beta, out);
}

// Round 17
// 234.233 us; speedup vs baseline: 1.0667x; 1.0667x over previous
//
#include <hip/hip_runtime.h>
#include <hip/hip_bf16.h>

typedef short bf16x8 __attribute__((ext_vector_type(8)));
typedef float f32x4  __attribute__((ext_vector_type(4)));
typedef unsigned int u32;

#define LSEQ 2048
#define DDIM 512
#define NBAT 8

__device__ __forceinline__ void gld_lds16(const void* g, void* l) {
    __builtin_amdgcn_global_load_lds(
        (const __attribute__((address_space(1))) u32*)g,
        (__attribute__((address_space(3))) u32*)l, 16, 0, 0);
}
__device__ __forceinline__ float bf2f(short s) {
    u32 u = ((u32)(unsigned short)s) << 16;
    union { u32 u; float f; } c; c.u = u; return c.f;
}
__device__ __forceinline__ short f2bf(float f) {
    __hip_bfloat16 h = __float2bfloat16(f);
    return *(short*)&h;
}

// ---------------- merged conversions: blocks [0,1024) transpose W, rest convert x ----------------
__global__ void k_cvt(const float* __restrict__ x, const float* __restrict__ Wq,
                      const float* __restrict__ Wk, const float* __restrict__ Wv,
                      const float* __restrict__ Wo, __hip_bfloat16* __restrict__ xb,
                      __hip_bfloat16* __restrict__ Wtqkv, __hip_bfloat16* __restrict__ Wto) {
    __shared__ float t[32][33];
    if (blockIdx.x < 1024) {
        int mat = blockIdx.x >> 8;
        int tb  = blockIdx.x & 255;
        int tk  = tb >> 4, tn = tb & 15;
        const float* W = (mat == 0) ? Wq : (mat == 1) ? Wk : (mat == 2) ? Wv : Wo;
        int c  = threadIdx.x & 31;
        int r0 = threadIdx.x >> 5;
#pragma unroll
        for (int i = 0; i < 4; ++i) {
            int r = r0 + i * 8;
            t[r][c] = W[(size_t)(tk * 32 + r) * 512 + tn * 32 + c];
        }
        __syncthreads();
        __hip_bfloat16* dst = (mat < 3) ? (Wtqkv + (size_t)mat * 512 * 512) : Wto;
#pragma unroll
        for (int i = 0; i < 4; ++i) {
            int n = r0 + i * 8;
            dst[(size_t)(tn * 32 + n) * 512 + tk * 32 + c] = __float2bfloat16(t[c][n]);
        }
    } else {
        size_t i = ((size_t)(blockIdx.x - 1024) * 256 + threadIdx.x) * 4;
        float4 v = *(const float4*)(x + i);
        __hip_bfloat16 h[4] = { __float2bfloat16(v.x), __float2bfloat16(v.y),
                                __float2bfloat16(v.z), __float2bfloat16(v.w) };
        *(short4*)(xb + i) = *(short4*)h;
    }
}

// ---------------- fused QKV GEMM: double-buffered gld_lds staging, ONE barrier/iter ----------------
__global__ __launch_bounds__(256, 2)
void k_gemm_qkv(const __hip_bfloat16* __restrict__ A, const __hip_bfloat16* __restrict__ Bt,
                __hip_bfloat16* __restrict__ Q, __hip_bfloat16* __restrict__ Kb,
                __hip_bfloat16* __restrict__ Vt) {
    __shared__ __hip_bfloat16 As[2][128][32], Bs[2][128][32];   // 32 KB
    const int tid = threadIdx.x, lane = tid & 63, w = tid >> 6;
    const int l15 = lane & 15, l4 = lane >> 4;
    const int mt = blockIdx.x, nt = blockIdx.y;
    const int wr = (w >> 1) * 64, wc = (w & 1) * 64;
    const int sr = lane >> 2, so = (lane & 3) * 8;
    f32x4 acc[4][4] = {};

    // prologue: stage kt=0 into buf 0
#pragma unroll
    for (int i = 0; i < 2; ++i) {
        int r0 = w * 32 + i * 16;
        gld_lds16(A  + (size_t)(mt * 128 + r0 + sr) * 512 + so, &As[0][r0][0]);
        gld_lds16(Bt + (size_t)(nt * 128 + r0 + sr) * 512 + so, &Bs[0][r0][0]);
    }
    __syncthreads();

#pragma unroll 1
    for (int kt = 0; kt < 16; ++kt) {
        const int cur = kt & 1, nxt = cur ^ 1;
        // issue staging for kt+1 (DMA overlaps MFMA below)
        if (kt < 15) {
#pragma unroll
            for (int i = 0; i < 2; ++i) {
                int r0 = w * 32 + i * 16;
                gld_lds16(A  + (size_t)(mt * 128 + r0 + sr) * 512 + (kt + 1) * 32 + so, &As[nxt][r0][0]);
                gld_lds16(Bt + (size_t)(nt * 128 + r0 + sr) * 512 + (kt + 1) * 32 + so, &Bs[nxt][r0][0]);
            }
        }
        bf16x8 af[4], bfr[4];
#pragma unroll
        for (int i = 0; i < 4; ++i)
            af[i] = *(const bf16x8*)(&As[cur][wr + 16 * i + l15][l4 * 8]);
#pragma unroll
        for (int j = 0; j < 4; ++j)
            bfr[j] = *(const bf16x8*)(&Bs[cur][wc + 16 * j + l15][l4 * 8]);
        __builtin_amdgcn_s_setprio(1);
#pragma unroll
        for (int i = 0; i < 4; ++i)
#pragma unroll
            for (int j = 0; j < 4; ++j)
                acc[i][j] = __builtin_amdgcn_mfma_f32_16x16x32_bf16(af[i], bfr[j], acc[i][j], 0, 0, 0);
        __builtin_amdgcn_s_setprio(0);
        __syncthreads();   // drains DMA (buf nxt ready) + protects buf cur from next stage
    }
    const int which = (nt * 128) >> 9;  // 0=q,1=k,2=v (uniform per block)
#pragma unroll
    for (int i = 0; i < 4; ++i) {
#pragma unroll
        for (int r = 0; r < 4; ++r) {
            int grow = mt * 128 + wr + 16 * i + (l4 << 2) + r;
#pragma unroll
            for (int j = 0; j < 4; ++j) {
                int gcol = nt * 128 + wc + 16 * j + l15;
                int cc = gcol & 511;
                __hip_bfloat16 h = __float2bfloat16(acc[i][j][r]);
                if (which == 0)      Q [(size_t)grow * 512 + cc] = h;
                else if (which == 1) Kb[(size_t)grow * 512 + cc] = h;
                else {
                    int b = grow >> 11, m = grow & 2047;
                    Vt[((size_t)b * 512 + cc) * 2048 + m] = h;
                }
            }
        }
    }
}

// ---------------- flash attention: 8 waves, dbuf KVB=32, all-async staging (R8-proven, FROZEN) ----------------
__global__ __launch_bounds__(512, 2)
void k_attn(const __hip_bfloat16* __restrict__ Q, const __hip_bfloat16* __restrict__ Kg,
            const __hip_bfloat16* __restrict__ Vt, const int* __restrict__ adj,
            __hip_bfloat16* __restrict__ P0, __hip_bfloat16* __restrict__ P1,
            float* __restrict__ mlb) {
    __shared__ __hip_bfloat16 Kl[2][32][520];   // 66,560 B
    __shared__ __hip_bfloat16 Vl[2][512][32];   // 65,536 B (linear 64B rows, swizzled 16B cols)
    __shared__ __hip_bfloat16 Pl[8][16][40];    // 10,240 B => 142,336 B total
    const int tid = threadIdx.x, lane = tid & 63, w = tid >> 6;
    const int l15 = lane & 15, l4 = lane >> 4;
    const int b = blockIdx.x & 7, qt = (blockIdx.x >> 3) & 15, s = blockIdx.x >> 7;
    const float scale = 0.04419417382415922f;  // 1/sqrt(512)
    __hip_bfloat16* __restrict__ Op = s ? P1 : P0;

    const __hip_bfloat16* kbase = Kg + ((size_t)b * LSEQ + s * 1024) * 512;
    const __hip_bfloat16* vbase = Vt + (size_t)b * 512 * 2048 + s * 1024;
    const int* abase = adj + ((size_t)b * LSEQ + qt * 128 + w * 16 + l4 * 4) * LSEQ + s * 1024 + l15;
    const int vsr = lane >> 2;                       // V staging row within 16-row chunk
    const int vswz = (l4 ^ ((l15 >> 1) & 3)) * 8;    // PV read swizzle (element offset)

    // Q fragments in registers: wave's 16 rows x 512 k
    bf16x8 qf[16];
    {
        const __hip_bfloat16* qp = Q + ((size_t)b * LSEQ + qt * 128 + w * 16 + l15) * 512;
#pragma unroll
        for (int ks = 0; ks < 16; ++ks)
            qf[ks] = *(const bf16x8*)(qp + ks * 32 + l4 * 8);
    }
    f32x4 acc[32];
#pragma unroll
    for (int n = 0; n < 32; ++n) acc[n] = (f32x4){0.f, 0.f, 0.f, 0.f};
    float m_[4] = {-1e30f, -1e30f, -1e30f, -1e30f};
    float l_[4] = {0.f, 0.f, 0.f, 0.f};

    int adjv[8];
    // ---- prologue: stage tile 0 into buf 0 ----
    {
#pragma unroll
        for (int i = 0; i < 4; ++i) {
            int r = w + i * 8;
            gld_lds16(kbase + (size_t)r * 512 + lane * 8, &Kl[0][r][0]);
        }
#pragma unroll
        for (int i = 0; i < 4; ++i) {
            int r0 = (w * 4 + i) * 16;
            int d  = r0 + vsr;
            gld_lds16(vbase + (size_t)d * 2048 + (((lane & 3) ^ ((d >> 1) & 3)) << 3), &Vl[0][r0][0]);
        }
#pragma unroll
        for (int r = 0; r < 4; ++r)
#pragma unroll
            for (int n = 0; n < 2; ++n)
                adjv[r * 2 + n] = abase[(size_t)r * LSEQ + n * 16];
    }
    __syncthreads();   // drains all global_load_lds

#pragma unroll 1
    for (int t = 0; t < 32; ++t) {
        const int cur = t & 1, nxt = cur ^ 1;
        unsigned amask = 0;
#pragma unroll
        for (int r = 0; r < 4; ++r)
#pragma unroll
            for (int n = 0; n < 2; ++n)
                amask |= (adjv[r * 2 + n] != 0 ? 1u : 0u) << (n * 4 + r);
        // ---- issue staging for t+1 (overlaps with compute below) ----
        if (t < 31) {
            const __hip_bfloat16* kp = kbase + (size_t)(t + 1) * 32 * 512;
#pragma unroll
            for (int i = 0; i < 4; ++i) {
                int r = w + i * 8;
                gld_lds16(kp + (size_t)r * 512 + lane * 8, &Kl[nxt][r][0]);
            }
            const __hip_bfloat16* vp = vbase + (t + 1) * 32;
#pragma unroll
            for (int i = 0; i < 4; ++i) {
                int r0 = (w * 4 + i) * 16;
                int d  = r0 + vsr;
                gld_lds16(vp + (size_t)d * 2048 + (((lane & 3) ^ ((d >> 1) & 3)) << 3), &Vl[nxt][r0][0]);
            }
            const int* ap = abase + (t + 1) * 32;
#pragma unroll
            for (int r = 0; r < 4; ++r)
#pragma unroll
                for (int n = 0; n < 2; ++n)
                    adjv[r * 2 + n] = ap[(size_t)r * LSEQ + n * 16];
        }
        // ---- QK^T on buf cur: wave's 16 rows x 32 keys ----
        f32x4 sa[2];
#pragma unroll
        for (int n = 0; n < 2; ++n) sa[n] = (f32x4){0.f, 0.f, 0.f, 0.f};
        __builtin_amdgcn_s_setprio(1);
#pragma unroll
        for (int ks = 0; ks < 16; ++ks) {
#pragma unroll
            for (int n = 0; n < 2; ++n) {
                bf16x8 bk = *(const bf16x8*)(&Kl[cur][n * 16 + l15][ks * 32 + l4 * 8]);
                sa[n] = __builtin_amdgcn_mfma_f32_16x16x32_bf16(qf[ks], bk, sa[n], 0, 0, 0);
            }
        }
        __builtin_amdgcn_s_setprio(0);
        // masked row max
        float mx[4];
#pragma unroll
        for (int r = 0; r < 4; ++r) {
            float v = -1e30f;
#pragma unroll
            for (int n = 0; n < 2; ++n)
                if ((amask >> (n * 4 + r)) & 1) v = fmaxf(v, sa[n][r] * scale);
            v = fmaxf(v, __shfl_xor(v, 1));
            v = fmaxf(v, __shfl_xor(v, 2));
            v = fmaxf(v, __shfl_xor(v, 4));
            v = fmaxf(v, __shfl_xor(v, 8));
            mx[r] = v;
        }
        // deferred-max online softmax (THR=8)
        float rs[4];
        bool need = false;
#pragma unroll
        for (int r = 0; r < 4; ++r) {
            rs[r] = 1.f;
            if (mx[r] > m_[r] + 8.f) { rs[r] = __expf(m_[r] - mx[r]); m_[r] = mx[r]; }
            l_[r] *= rs[r];
            need |= (rs[r] != 1.f);
        }
        if (need) {
#pragma unroll
            for (int n = 0; n < 32; ++n) {
                acc[n][0] *= rs[0]; acc[n][1] *= rs[1];
                acc[n][2] *= rs[2]; acc[n][3] *= rs[3];
            }
        }
        // p = exp(s - m) (masked -> 0); row sums
#pragma unroll
        for (int n = 0; n < 2; ++n)
#pragma unroll
            for (int r = 0; r < 4; ++r) {
                float p = ((amask >> (n * 4 + r)) & 1) ? __expf(sa[n][r] * scale - m_[r]) : 0.f;
                sa[n][r] = p;
            }
#pragma unroll
        for (int r = 0; r < 4; ++r) {
            float sm = sa[0][r] + sa[1][r];
            sm += __shfl_xor(sm, 1);
            sm += __shfl_xor(sm, 2);
            sm += __shfl_xor(sm, 4);
            sm += __shfl_xor(sm, 8);
            l_[r] += sm;
        }
        // relayout P via per-wave LDS
#pragma unroll
        for (int n = 0; n < 2; ++n)
#pragma unroll
            for (int r = 0; r < 4; ++r)
                Pl[w][l4 * 4 + r][n * 16 + l15] = __float2bfloat16(sa[n][r]);
        // PV accumulate on buf cur (swizzled V read)
        {
            bf16x8 pf = *(const bf16x8*)(&Pl[w][l15][l4 * 8]);
            __builtin_amdgcn_s_setprio(1);
#pragma unroll
            for (int n = 0; n < 32; ++n) {
                bf16x8 bv = *(const bf16x8*)(&Vl[cur][n * 16 + l15][vswz]);
                acc[n] = __builtin_amdgcn_mfma_f32_16x16x32_bf16(pf, bv, acc[n], 0, 0, 0);
            }
            __builtin_amdgcn_s_setprio(0);
        }
        __syncthreads();   // publishes buf nxt
    }
    // epilogue: unnormalized partials + (m,l)
#pragma unroll
    for (int r = 0; r < 4; ++r) {
        size_t row = (size_t)b * LSEQ + qt * 128 + w * 16 + l4 * 4 + r;
#pragma unroll
        for (int n = 0; n < 32; ++n)
            Op[row * 512 + n * 16 + l15] = __float2bfloat16(acc[n][r]);
        if (l15 == 0) {
            mlb[((size_t)s * 16384 + row) * 2 + 0] = m_[r];
            mlb[((size_t)s * 16384 + row) * 2 + 1] = l_[r];
        }
    }
}

// ---------------- fused: combine(LSE) + out-proj + residual + bias + LayerNorm ----------------
// grid 256: block = 64 rows x 512 cols. Double-buffered; A-combine uses T14 load-early/write-late.
__global__ __launch_bounds__(512, 2)
void k_out_ln(const __hip_bfloat16* __restrict__ p0, const __hip_bfloat16* __restrict__ p1,
              const float* __restrict__ mlb, const __hip_bfloat16* __restrict__ Bt,
              const float* __restrict__ x, const float* __restrict__ bo,
              const float* __restrict__ gamma, const float* __restrict__ beta,
              float* __restrict__ out) {
    __shared__ __hip_bfloat16 As[2][64][32];   //  8 KB
    __shared__ __hip_bfloat16 Bs[2][512][32];  // 64 KB
    __shared__ float part[64][4][2];           //  2 KB
    __shared__ float lnmv[64][2];              //  0.5 KB => 74.5 KB
    const int tid = threadIdx.x, lane = tid & 63, w = tid >> 6;
    const int l15 = lane & 15, l4 = lane >> 4;
    const int mt = blockIdx.x;
    const int rs = (w >> 2) * 32, cbs = (w & 3) * 128;
    f32x4 acc[2][8] = {};

    // per-row combine factors (A-staging threads: tid<256, row = tid>>2)
    float c0 = 0.f, c1 = 0.f;
    size_t grow_s = 0;
    int ko = (tid & 3) * 8;
    if (tid < 256) {
        int arow = tid >> 2;
        grow_s = (size_t)mt * 64 + arow;
        float m0 = mlb[grow_s * 2], l0 = mlb[grow_s * 2 + 1];
        float m1 = mlb[(16384 + grow_s) * 2], l1 = mlb[(16384 + grow_s) * 2 + 1];
        float M  = fmaxf(m0, m1);
        float e0 = __expf(m0 - M), e1 = __expf(m1 - M);
        float den = l0 * e0 + l1 * e1;
        float inv = (den > 0.f) ? 1.f / den : 0.f;
        c0 = e0 * inv; c1 = e1 * inv;
    }

    // prologue: stage kt=0 into buf 0
#pragma unroll
    for (int i = 0; i < 4; ++i) {
        int br = w * 64 + i * 16;
        gld_lds16(Bt + (size_t)(br + (lane >> 2)) * 512 + (lane & 3) * 8, &Bs[0][br][0]);
    }
    if (tid < 256) {
        bf16x8 a0 = *(const bf16x8*)(p0 + grow_s * 512 + ko);
        bf16x8 a1 = *(const bf16x8*)(p1 + grow_s * 512 + ko);
        short h[8];
#pragma unroll
        for (int k = 0; k < 8; ++k)
            h[k] = f2bf(c0 * bf2f(((short*)&a0)[k]) + c1 * bf2f(((short*)&a1)[k]));
        *(bf16x8*)(&As[0][tid >> 2][ko]) = *(bf16x8*)h;
    }
    __syncthreads();

#pragma unroll 1
    for (int kt = 0; kt < 16; ++kt) {
        const int cur = kt & 1, nxt = cur ^ 1;
        bf16x8 a0, a1;
        // issue staging for kt+1: B via DMA, A partials into regs (write-late)
        if (kt < 15) {
#pragma unroll
            for (int i = 0; i < 4; ++i) {
                int br = w * 64 + i * 16;
                gld_lds16(Bt + (size_t)(br + (lane >> 2)) * 512 + (kt + 1) * 32 + (lane & 3) * 8,
                          &Bs[nxt][br][0]);
            }
            if (tid < 256) {
                a0 = *(const bf16x8*)(p0 + grow_s * 512 + (kt + 1) * 32 + ko);
                a1 = *(const bf16x8*)(p1 + grow_s * 512 + (kt + 1) * 32 + ko);
            }
        }
        bf16x8 af[2], bfr[8];
#pragma unroll
        for (int i = 0; i < 2; ++i)
            af[i] = *(const bf16x8*)(&As[cur][rs + 16 * i + l15][l4 * 8]);
#pragma unroll
        for (int j = 0; j < 8; ++j)
            bfr[j] = *(const bf16x8*)(&Bs[cur][cbs + 16 * j + l15][l4 * 8]);
        __builtin_amdgcn_s_setprio(1);
#pragma unroll
        for (int i = 0; i < 2; ++i)
#pragma unroll
            for (int j = 0; j < 8; ++j)
                acc[i][j] = __builtin_amdgcn_mfma_f32_16x16x32_bf16(af[i], bfr[j], acc[i][j], 0, 0, 0);
        __builtin_amdgcn_s_setprio(0);
        // A-combine write-late (loads landed under the MFMA block)
        if (kt < 15 && tid < 256) {
            short h[8];
#pragma unroll
            for (int k = 0; k < 8; ++k)
                h[k] = f2bf(c0 * bf2f(((short*)&a0)[k]) + c1 * bf2f(((short*)&a1)[k]));
            *(bf16x8*)(&As[nxt][tid >> 2][ko]) = *(bf16x8*)h;
        }
        __syncthreads();   // drains B-DMA + A ds_writes; protects buf cur
    }
    // pass 1: y = x + acc + bo (into acc), LN partials
#pragma unroll
    for (int i = 0; i < 2; ++i) {
#pragma unroll
        for (int r = 0; r < 4; ++r) {
            int rl = rs + 16 * i + 4 * l4 + r;
            size_t grow = (size_t)mt * 64 + rl;
            float s = 0.f, q = 0.f;
#pragma unroll
            for (int j = 0; j < 8; ++j) {
                int col = cbs + 16 * j + l15;
                float y = x[grow * 512 + col] + acc[i][j][r] + bo[col];
                acc[i][j][r] = y;
                s += y; q += y * y;
            }
            s += __shfl_xor(s, 1); q += __shfl_xor(q, 1);
            s += __shfl_xor(s, 2); q += __shfl_xor(q, 2);
            s += __shfl_xor(s, 4); q += __shfl_xor(q, 4);
            s += __shfl_xor(s, 8); q += __shfl_xor(q, 8);
            if (l15 == 0) { part[rl][w & 3][0] = s; part[rl][w & 3][1] = q; }
        }
    }
    __syncthreads();
    if (tid < 64) {
        float S  = part[tid][0][0] + part[tid][1][0] + part[tid][2][0] + part[tid][3][0];
        float Q2 = part[tid][0][1] + part[tid][1][1] + part[tid][2][1] + part[tid][3][1];
        float mu = S * (1.f / 512.f);
        float var = Q2 * (1.f / 512.f) - mu * mu;
        lnmv[tid][0] = mu;
        lnmv[tid][1] = rsqrtf(var + 1e-5f);
    }
    __syncthreads();
    // pass 2: normalize + store
    float gm[8], bt2[8];
#pragma unroll
    for (int j = 0; j < 8; ++j) {
        int col = cbs + 16 * j + l15;
        gm[j] = gamma[col]; bt2[j] = beta[col];
    }
#pragma unroll
    for (int i = 0; i < 2; ++i) {
#pragma unroll
        for (int r = 0; r < 4; ++r) {
            int rl = rs + 16 * i + 4 * l4 + r;
            size_t grow = (size_t)mt * 64 + rl;
            float mu = lnmv[rl][0], rsd = lnmv[rl][1];
#pragma unroll
            for (int j = 0; j < 8; ++j) {
                int col = cbs + 16 * j + l15;
                out[grow * 512 + col] = (acc[i][j][r] - mu) * rsd * gm[j] + bt2[j];
            }
        }
    }
}

extern "C" void kernel_launch(void* const* d_in, const int* in_sizes, int n_in,
                              void* d_out, int out_size, void* d_ws, size_t ws_size,
                              hipStream_t stream) {
    const float* x     = (const float*)d_in[0];
    const int*   adj   = (const int*)d_in[1];
    const float* Wq    = (const float*)d_in[2];
    const float* Wk    = (const float*)d_in[3];
    const float* Wv    = (const float*)d_in[4];
    const float* Wo    = (const float*)d_in[5];
    const float* bo    = (const float*)d_in[6];
    const float* gamma = (const float*)d_in[7];
    const float* beta  = (const float*)d_in[8];
    float* out = (float*)d_out;

    char* ws = (char*)d_ws;
    const size_t SZ_ROWS = (size_t)NBAT * LSEQ;  // 16384
    __hip_bfloat16* xb    = (__hip_bfloat16*)(ws);              // 16.78 MB; later = partial0
    __hip_bfloat16* Wtqkv = (__hip_bfloat16*)(ws + 16777216);   // 1.57 MB
    __hip_bfloat16* Wto   = (__hip_bfloat16*)(ws + 18350080);   // 0.52 MB
    __hip_bfloat16* Qb    = (__hip_bfloat16*)(ws + 18874368);   // 16.78 MB
    __hip_bfloat16* Kb    = (__hip_bfloat16*)(ws + 35651584);   // 16.78 MB
    __hip_bfloat16* Vtb   = (__hip_bfloat16*)(ws + 52428800);   // 16.78 MB
    __hip_bfloat16* P1    = (__hip_bfloat16*)(ws + 69206016);   // 16.78 MB (partial1)
    float*          mlb   = (float*)         (ws + 85983232);   // 0.26 MB
    __hip_bfloat16* P0    = xb;   // partial0 alias (xb dead after gemm_qkv)
    (void)in_sizes; (void)n_in; (void)out_size; (void)ws_size;

    k_cvt<<<1024 + (unsigned)((SZ_ROWS * DDIM) / (256 * 4)), 256, 0, stream>>>(
        x, Wq, Wk, Wv, Wo, xb, Wtqkv, Wto);
    k_gemm_qkv<<<dim3(128, 12), 256, 0, stream>>>(xb, Wtqkv, Qb, Kb, Vtb);
    k_attn<<<256, 512, 0, stream>>>(Qb, Kb, Vtb, adj, P0, P1, mlb);
    k_out_ln<<<256, 512, 0, stream>>>(P0, P1, mlb, Wto, x, bo, gamma, beta, out);
}